// Round 4
// baseline (573.049 us; speedup 1.0000x reference)
//
#include <hip/hip_runtime.h>
#include <math.h>

#define D_DIM 2048
#define NE    64
#define NTOK  16384
#define TK    8
#define TOKB  32                  // tokens per block
#define KS    8                   // K-split across the 8 waves
#define KD    (D_DIM / KS)        // 256 d per wave
#define KCH   32                  // d per chunk per wave
#define NCH   (KD / KCH)          // 8 chunks
#define BT    512                 // 8 waves

#define XSF   (KS * TOKB * KCH)   // 8192 floats per staging buffer (32 KB)
#define RROW  72                  // 64 + 8 pad for reduction rows
#define POOLF (KS * TOKB * RROW)  // 18432 floats = 72 KB (>= 2*XSF)

#define OUT_I_OFF (NTOK * TK)
#define OUT_S_OFF (2 * NTOK * TK)

#define GLOBAL_AS __attribute__((address_space(1)))
#define LDS_AS    __attribute__((address_space(3)))

static __device__ __forceinline__ void async_copy16(const float* g, float* l) {
    // offset immediate ALWAYS 0 (non-zero LDS-DMA offsets are unverified on gfx950
    // and were the prime suspect in the r2 correctness failure).
    __builtin_amdgcn_global_load_lds((const GLOBAL_AS void*)g, (LDS_AS void*)l, 16, 0, 0);
}

// Single fused kernel: scores = sigmoid(x.w^T)+gb, then per-block top-8+normalize.
// Block: 32 tokens, 8 waves = K-split 8 (256 d each). Lane (lt=lane>>3, le=lane&7),
// per-lane tile 4 tokens x 8 experts. x: global_load_lds dbuf, quad-XOR swizzle
// (swizzle on GLOBAL source, linear LDS dest). w: per-lane divergent float4 global
// loads (L2-resident), wa/wb 1-step prefetch. Grid 512 = 2 independent blocks/CU
// so blocks' barrier stalls interleave; launch_bounds(512,4) caps VGPR at 128.
__global__ __launch_bounds__(BT, 4) void gate_fused(const float* __restrict__ x,
                                                    const float* __restrict__ w,
                                                    const float* __restrict__ gb,
                                                    float* __restrict__ out) {
    __shared__ __align__(16) float pool[POOLF];

    float* scores = out + OUT_S_OFF;
    const int tid  = threadIdx.x;
    const int lane = tid & 63;
    const int ks   = tid >> 6;     // wave id = K-split slice
    const int lt   = lane >> 3;    // token slot
    const int le   = lane & 7;     // expert slot
    const int tok0 = blockIdx.x * TOKB;

    // w row pointers: expert j*8+le, this wave's d-slice. le-divergent -> vector loads.
    const float4* wp[8];
#pragma unroll
    for (int j = 0; j < 8; ++j)
        wp[j] = (const float4*)w + (size_t)(j * 8 + le) * (D_DIM / 4) + ks * (KD / 4);

    // staging map: quad index Q = tid + 512k decomposes as [ks][t][slot] with
    // ks = ks0+2k, t = tt, slot = qp. Physical slot qp holds LOGICAL quad
    // dq0 = qp ^ (tt&7) (self-inverse swizzle on the GLOBAL source side).
    const int ks0 = tid >> 8;
    const int tt  = (tid & 255) >> 3;
    const int qp  = tid & 7;
    const int dq0 = qp ^ (tt & 7);
    const float* srcq[4];
#pragma unroll
    for (int k = 0; k < 4; ++k)
        srcq[k] = x + (size_t)(tok0 + tt) * D_DIM + (ks0 + 2 * k) * KD + dq0 * 4;

    auto stage = [&](int c, int buf) {
        float* d = pool + buf * XSF + tid * 4;
#pragma unroll
        for (int k = 0; k < 4; ++k)
            async_copy16(srcq[k] + c * KCH, d + k * 2048);
    };

    float acc[4][8];
#pragma unroll
    for (int i = 0; i < 4; ++i)
#pragma unroll
        for (int j = 0; j < 8; ++j) acc[i][j] = 0.f;

    float4 wa[8], wb[8];
#pragma unroll
    for (int j = 0; j < 8; ++j) wa[j] = wp[j][0];
    stage(0, 0);

    // one step = 4 d: FMA on WC (resident), prefetch next quad into WN.
    auto step = [&](float4 (&WC)[8], float4 (&WN)[8], const float* xs, int c4n, int dq) {
#pragma unroll
        for (int j = 0; j < 8; ++j) WN[j] = wp[j][c4n];
        const float* xb = xs + ((dq ^ lt) << 2);
        float4 xi[4];
#pragma unroll
        for (int i = 0; i < 4; ++i) xi[i] = *(const float4*)(xb + i * 256);
#pragma unroll
        for (int i = 0; i < 4; ++i) {
#pragma unroll
            for (int j = 0; j < 8; ++j) {
                acc[i][j] = fmaf(xi[i].x, WC[j].x, acc[i][j]);
                acc[i][j] = fmaf(xi[i].y, WC[j].y, acc[i][j]);
                acc[i][j] = fmaf(xi[i].z, WC[j].z, acc[i][j]);
                acc[i][j] = fmaf(xi[i].w, WC[j].w, acc[i][j]);
            }
        }
    };

    for (int c = 0; c < NCH; ++c) {
        __syncthreads();                          // stage(c) drained (vmcnt0@barrier)
        const float* xs = pool + (c & 1) * XSF + ks * (TOKB * KCH) + lt * KCH;
        const int cb = c * 8;
        step(wa, wb, xs, (cb + 1) & 63, 0);
        step(wb, wa, xs, (cb + 2) & 63, 1);
        if (c + 1 < NCH) stage(c + 1, (c + 1) & 1);   // issued after 2 steps: w-waits
        step(wa, wb, xs, (cb + 3) & 63, 2);           // before this don't drain staging
        step(wb, wa, xs, (cb + 4) & 63, 3);
        step(wa, wb, xs, (cb + 5) & 63, 4);
        step(wb, wa, xs, (cb + 6) & 63, 5);
        step(wa, wb, xs, (cb + 7) & 63, 6);
        step(wb, wa, xs, (cb + 8) & 63, 7);
    }

    // ---- split-K reduction (padded rows: bank-spread) ----
    __syncthreads();
    {
        const int rb = ks * (TOKB * RROW);
#pragma unroll
        for (int i = 0; i < 4; ++i)
#pragma unroll
            for (int j = 0; j < 8; ++j)
                pool[rb + (i * 8 + lt) * RROW + j * 8 + le] = acc[i][j];
    }
    __syncthreads();
    float sc4[4];
    {
        const int t = tid >> 4;        // token 0..31
        const int q = tid & 15;        // expert-quad 0..15
        float4 s = {0.f, 0.f, 0.f, 0.f};
#pragma unroll
        for (int k = 0; k < KS; ++k) {
            float4 a = *(const float4*)(pool + k * (TOKB * RROW) + t * RROW + q * 4);
            s.x += a.x; s.y += a.y; s.z += a.z; s.w += a.w;
        }
        float4 g = *(const float4*)(gb + q * 4);
        sc4[0] = 1.f / (1.f + expf(-s.x)) + g.x;
        sc4[1] = 1.f / (1.f + expf(-s.y)) + g.y;
        sc4[2] = 1.f / (1.f + expf(-s.z)) + g.z;
        sc4[3] = 1.f / (1.f + expf(-s.w)) + g.w;
        float* so = scores + (size_t)(tok0 + t) * NE + q * 4;
        float4 v = {sc4[0], sc4[1], sc4[2], sc4[3]};
        *(float4*)so = v;
    }
    __syncthreads();                   // all reduction reads done -> reuse pool[0..2048)
    {
        const int t = tid >> 4;
        const int q = tid & 15;
        float4 v = {sc4[0], sc4[1], sc4[2], sc4[3]};
        *(float4*)(pool + t * NE + q * 4) = v;
    }
    __syncthreads();

    // ---- fused top-8 + normalize (4 lanes per token; ties -> lower index) ----
    if (tid < 128) {
        const int t  = tid >> 2;       // token 0..31
        const int q4 = tid & 3;
        float v[16];
        const float4* sp = (const float4*)(pool + t * NE + q4 * 16);
        float4 a = sp[0], b = sp[1], c = sp[2], d = sp[3];
        v[0] = a.x;  v[1] = a.y;  v[2] = a.z;  v[3] = a.w;
        v[4] = b.x;  v[5] = b.y;  v[6] = b.z;  v[7] = b.w;
        v[8] = c.x;  v[9] = c.y;  v[10] = c.z; v[11] = c.w;
        v[12] = d.x; v[13] = d.y; v[14] = d.z; v[15] = d.w;

        float kv[TK]; int ki[TK];
#pragma unroll
        for (int k = 0; k < TK; ++k) {
            float bv = v[0]; int bi = q4 * 16;
#pragma unroll
            for (int j = 1; j < 16; ++j) {
                bool gt = v[j] > bv;
                bv = gt ? v[j] : bv;
                bi = gt ? (q4 * 16 + j) : bi;
            }
#pragma unroll
            for (int off = 1; off < 4; off <<= 1) {
                float ov = __shfl_xor(bv, off);
                int   oi = __shfl_xor(bi, off);
                bool take = (ov > bv) || (ov == bv && oi < bi);
                bv = take ? ov : bv;
                bi = take ? oi : bi;
            }
            int lj = bi - q4 * 16;
#pragma unroll
            for (int j = 0; j < 16; ++j) v[j] = (j == lj) ? -3e38f : v[j];
            kv[k] = bv; ki[k] = bi;
        }

        if (q4 == 0) {
            float s = 0.f;
#pragma unroll
            for (int k = 0; k < TK; ++k) s += kv[k];
            float inv = 1.f / s;
            float* ow = out + (size_t)(tok0 + t) * TK;
            float* oi = out + OUT_I_OFF + (size_t)(tok0 + t) * TK;
#pragma unroll
            for (int k = 0; k < TK; ++k) {
                ow[k] = kv[k] * inv;
                oi[k] = (float)ki[k];
            }
        }
    }
}

extern "C" void kernel_launch(void* const* d_in, const int* in_sizes, int n_in,
                              void* d_out, int out_size, void* d_ws, size_t ws_size,
                              hipStream_t stream) {
    const float* x  = (const float*)d_in[0];
    const float* w  = (const float*)d_in[1];
    const float* gb = (const float*)d_in[2];
    float* out = (float*)d_out;
    (void)in_sizes; (void)n_in; (void)out_size; (void)d_ws; (void)ws_size;

    gate_fused<<<dim3(NTOK / TOKB), dim3(BT), 0, stream>>>(x, w, gb, out);
}

// Round 5
// 407.672 us; speedup vs baseline: 1.4057x; 1.4057x over previous
//
#include <hip/hip_runtime.h>
#include <math.h>

#define D_DIM 2048
#define NE    64
#define NTOK  16384
#define TK    8
#define TOKB  32                  // tokens per block
#define KS    8                   // K-split across the 8 waves
#define KD    (D_DIM / KS)        // 256 d per wave
#define KCH   32                  // d per chunk per wave
#define NCH   (KD / KCH)          // 8 chunks
#define BT    512                 // 8 waves

#define XSF   (KS * TOKB * KCH)   // 8192 floats per staging buffer (32 KB)
#define RROW  72                  // 64 + 8 pad for reduction rows
#define POOLF (KS * TOKB * RROW)  // 18432 floats = 72 KB (>= 2*XSF)

#define OUT_I_OFF (NTOK * TK)
#define OUT_S_OFF (2 * NTOK * TK)

#define GLOBAL_AS __attribute__((address_space(1)))
#define LDS_AS    __attribute__((address_space(3)))

static __device__ __forceinline__ void async_copy16(const float* g, float* l) {
    // offset immediate ALWAYS 0 (r2 lesson: non-zero LDS-DMA offset corrupted staging).
    __builtin_amdgcn_global_load_lds((const GLOBAL_AS void*)g, (LDS_AS void*)l, 16, 0, 0);
}

// Single fused kernel: scores = sigmoid(x.w^T)+gb, then per-block top-8+normalize.
// Block: 32 tokens, 8 waves = K-split 8 (256 d each). Lane (lt=lane>>3, le=lane&7),
// per-lane tile 4 tokens x 8 experts. x: global_load_lds dbuf, quad-XOR swizzle
// (swizzle on GLOBAL source, linear LDS dest). w: per-lane divergent float4 global
// loads (L2-resident), wa/wb 1-step prefetch.
// __launch_bounds__(512,2): empirically cap=256/arg -> 128 VGPR. r4's (512,4)
// capped at 64 VGPR -> ~80-reg spill -> 716 MB scratch writes, 3.4x regression.
// 128 fits this kernel's ~145-reg peak with negligible spill (r1 precedent),
// and LDS 72 KB + 4 waves/SIMD still give 2 independent blocks/CU.
__global__ __launch_bounds__(BT, 2) void gate_fused(const float* __restrict__ x,
                                                    const float* __restrict__ w,
                                                    const float* __restrict__ gb,
                                                    float* __restrict__ out) {
    __shared__ __align__(16) float pool[POOLF];

    float* scores = out + OUT_S_OFF;
    const int tid  = threadIdx.x;
    const int lane = tid & 63;
    const int ks   = tid >> 6;     // wave id = K-split slice
    const int lt   = lane >> 3;    // token slot
    const int le   = lane & 7;     // expert slot
    const int tok0 = blockIdx.x * TOKB;

    // w row pointers: expert j*8+le, this wave's d-slice. le-divergent -> vector loads.
    const float4* wp[8];
#pragma unroll
    for (int j = 0; j < 8; ++j)
        wp[j] = (const float4*)w + (size_t)(j * 8 + le) * (D_DIM / 4) + ks * (KD / 4);

    // staging map: quad index Q = tid + 512k decomposes as [ks][t][slot] with
    // ks = ks0+2k, t = tt, slot = qp. Physical slot qp holds LOGICAL quad
    // dq0 = qp ^ (tt&7) (self-inverse swizzle on the GLOBAL source side).
    const int ks0 = tid >> 8;
    const int tt  = (tid & 255) >> 3;
    const int qp  = tid & 7;
    const int dq0 = qp ^ (tt & 7);
    const float* srcq[4];
#pragma unroll
    for (int k = 0; k < 4; ++k)
        srcq[k] = x + (size_t)(tok0 + tt) * D_DIM + (ks0 + 2 * k) * KD + dq0 * 4;

    auto stage = [&](int c, int buf) {
        float* d = pool + buf * XSF + tid * 4;
#pragma unroll
        for (int k = 0; k < 4; ++k)
            async_copy16(srcq[k] + c * KCH, d + k * 2048);
    };

    float acc[4][8];
#pragma unroll
    for (int i = 0; i < 4; ++i)
#pragma unroll
        for (int j = 0; j < 8; ++j) acc[i][j] = 0.f;

    float4 wa[8], wb[8];
#pragma unroll
    for (int j = 0; j < 8; ++j) wa[j] = wp[j][0];
    stage(0, 0);

    // one step = 4 d: FMA on WC (resident), prefetch next quad into WN.
    auto step = [&](float4 (&WC)[8], float4 (&WN)[8], const float* xs, int c4n, int dq) {
#pragma unroll
        for (int j = 0; j < 8; ++j) WN[j] = wp[j][c4n];
        const float* xb = xs + ((dq ^ lt) << 2);
        float4 xi[4];
#pragma unroll
        for (int i = 0; i < 4; ++i) xi[i] = *(const float4*)(xb + i * 256);
#pragma unroll
        for (int i = 0; i < 4; ++i) {
#pragma unroll
            for (int j = 0; j < 8; ++j) {
                acc[i][j] = fmaf(xi[i].x, WC[j].x, acc[i][j]);
                acc[i][j] = fmaf(xi[i].y, WC[j].y, acc[i][j]);
                acc[i][j] = fmaf(xi[i].z, WC[j].z, acc[i][j]);
                acc[i][j] = fmaf(xi[i].w, WC[j].w, acc[i][j]);
            }
        }
    };

    for (int c = 0; c < NCH; ++c) {
        __syncthreads();                          // stage(c) drained (vmcnt0@barrier)
        const float* xs = pool + (c & 1) * XSF + ks * (TOKB * KCH) + lt * KCH;
        const int cb = c * 8;
        step(wa, wb, xs, (cb + 1) & 63, 0);
        step(wb, wa, xs, (cb + 2) & 63, 1);
        if (c + 1 < NCH) stage(c + 1, (c + 1) & 1);   // issued after 2 steps: w-waits
        step(wa, wb, xs, (cb + 3) & 63, 2);           // before this don't drain staging
        step(wb, wa, xs, (cb + 4) & 63, 3);
        step(wa, wb, xs, (cb + 5) & 63, 4);
        step(wb, wa, xs, (cb + 6) & 63, 5);
        step(wa, wb, xs, (cb + 7) & 63, 6);
        step(wb, wa, xs, (cb + 8) & 63, 7);
    }

    // ---- split-K reduction (padded rows: bank-spread) ----
    __syncthreads();
    {
        const int rb = ks * (TOKB * RROW);
#pragma unroll
        for (int i = 0; i < 4; ++i)
#pragma unroll
            for (int j = 0; j < 8; ++j)
                pool[rb + (i * 8 + lt) * RROW + j * 8 + le] = acc[i][j];
    }
    __syncthreads();
    float sc4[4];
    {
        const int t = tid >> 4;        // token 0..31
        const int q = tid & 15;        // expert-quad 0..15
        float4 s = {0.f, 0.f, 0.f, 0.f};
#pragma unroll
        for (int k = 0; k < KS; ++k) {
            float4 a = *(const float4*)(pool + k * (TOKB * RROW) + t * RROW + q * 4);
            s.x += a.x; s.y += a.y; s.z += a.z; s.w += a.w;
        }
        float4 g = *(const float4*)(gb + q * 4);
        sc4[0] = 1.f / (1.f + expf(-s.x)) + g.x;
        sc4[1] = 1.f / (1.f + expf(-s.y)) + g.y;
        sc4[2] = 1.f / (1.f + expf(-s.z)) + g.z;
        sc4[3] = 1.f / (1.f + expf(-s.w)) + g.w;
        float* so = scores + (size_t)(tok0 + t) * NE + q * 4;
        float4 v = {sc4[0], sc4[1], sc4[2], sc4[3]};
        *(float4*)so = v;
    }
    __syncthreads();                   // all reduction reads done -> reuse pool[0..2048)
    {
        const int t = tid >> 4;
        const int q = tid & 15;
        float4 v = {sc4[0], sc4[1], sc4[2], sc4[3]};
        *(float4*)(pool + t * NE + q * 4) = v;
    }
    __syncthreads();

    // ---- fused top-8 + normalize (4 lanes per token; ties -> lower index) ----
    if (tid < 128) {
        const int t  = tid >> 2;       // token 0..31
        const int q4 = tid & 3;
        float v[16];
        const float4* sp = (const float4*)(pool + t * NE + q4 * 16);
        float4 a = sp[0], b = sp[1], c = sp[2], d = sp[3];
        v[0] = a.x;  v[1] = a.y;  v[2] = a.z;  v[3] = a.w;
        v[4] = b.x;  v[5] = b.y;  v[6] = b.z;  v[7] = b.w;
        v[8] = c.x;  v[9] = c.y;  v[10] = c.z; v[11] = c.w;
        v[12] = d.x; v[13] = d.y; v[14] = d.z; v[15] = d.w;

        float kv[TK]; int ki[TK];
#pragma unroll
        for (int k = 0; k < TK; ++k) {
            float bv = v[0]; int bi = q4 * 16;
#pragma unroll
            for (int j = 1; j < 16; ++j) {
                bool gt = v[j] > bv;
                bv = gt ? v[j] : bv;
                bi = gt ? (q4 * 16 + j) : bi;
            }
#pragma unroll
            for (int off = 1; off < 4; off <<= 1) {
                float ov = __shfl_xor(bv, off);
                int   oi = __shfl_xor(bi, off);
                bool take = (ov > bv) || (ov == bv && oi < bi);
                bv = take ? ov : bv;
                bi = take ? oi : bi;
            }
            int lj = bi - q4 * 16;
#pragma unroll
            for (int j = 0; j < 16; ++j) v[j] = (j == lj) ? -3e38f : v[j];
            kv[k] = bv; ki[k] = bi;
        }

        if (q4 == 0) {
            float s = 0.f;
#pragma unroll
            for (int k = 0; k < TK; ++k) s += kv[k];
            float inv = 1.f / s;
            float* ow = out + (size_t)(tok0 + t) * TK;
            float* oi = out + OUT_I_OFF + (size_t)(tok0 + t) * TK;
#pragma unroll
            for (int k = 0; k < TK; ++k) {
                ow[k] = kv[k] * inv;
                oi[k] = (float)ki[k];
            }
        }
    }
}

extern "C" void kernel_launch(void* const* d_in, const int* in_sizes, int n_in,
                              void* d_out, int out_size, void* d_ws, size_t ws_size,
                              hipStream_t stream) {
    const float* x  = (const float*)d_in[0];
    const float* w  = (const float*)d_in[1];
    const float* gb = (const float*)d_in[2];
    float* out = (float*)d_out;
    (void)in_sizes; (void)n_in; (void)out_size; (void)d_ws; (void)ws_size;

    gate_fused<<<dim3(NTOK / TOKB), dim3(BT), 0, stream>>>(x, w, gb, out);
}